// Round 4
// baseline (64.031 us; speedup 1.0000x reference)
//
#include <hip/hip_runtime.h>

#define OUT_HW 7
#define BINS   (OUT_HW * OUT_HW)  // 49
#define NCH    256
#define FH     38
#define FW     38
#define PLANE  (FH * FW)          // 1444 floats

// ===== SACRED boundary math (bit-exact vs checker, R17 absmax=0.0) =====
// XLA-CPU-fastmath emulation: span/7 -> span * rn32(1/7) (0x3E124925),
// oh*bin + start contracted to a single fmaf. Do not alter operations,
// order, or precision.
// =======================================================================

// Minimal-structure experiment (3rd submission — rounds 2 and 3 failed on
// container acquisition before the kernel ever ran; source audited, all
// accesses statically in-bounds, loops statically bounded):
// the feature tensor is 2.96 MB -> a wave's working set (~2 planes,
// 11.6 KB) fits L1; windows of adjacent bins overlap -> re-reads are
// L1/L2 hits. So LDS staging + __syncthreads is pure overhead. One
// thread per output element, direct global reads, single store.
// Compulsory traffic: 2.96 MB read + 3.2 MB write ~= 1 us at HBM BW.
__global__ __launch_bounds__(256) void roi_pool_kernel(
    const float* __restrict__ feat,
    const int*   __restrict__ rois,
    float*       __restrict__ out,
    int total)
{
    int o = blockIdx.x * 256 + threadIdx.x;
    if (o >= total) return;

    int p   = o / BINS;            // plane id = r*256 + c  (magic-mul)
    int bin = o - p * BINS;        // 0..48
    int r   = p >> 8;
    int c   = p & (NCH - 1);
    int oh  = bin / OUT_HW;
    int ow  = bin - oh * OUT_HW;

    const int* roi = rois + r * 5;
    int ridx = roi[0];

    // ---- SACRED window computation (identical ops to passing R17) ----
    float sw = (float)roi[1] * 0.0625f;
    float sh = (float)roi[2] * 0.0625f;
    float ew = (float)roi[3] * 0.0625f;
    float eh = (float)roi[4] * 0.0625f;

    const float C7 = __uint_as_float(0x3E124925u);   // rn32(1/7)
    float bw = __fmul_rn(fmaxf(ew - sw, 1.0f), C7);
    float bh = __fmul_rn(fmaxf(eh - sh, 1.0f), C7);

    int hs = (int)floorf(fmaf((float)oh,       bh, sh));
    int he = (int)ceilf (fmaf((float)(oh + 1), bh, sh));
    int ws = (int)floorf(fmaf((float)ow,       bw, sw));
    int we = (int)ceilf (fmaf((float)(ow + 1), bw, sw));

    hs = min(max(hs, 0), FH);
    he = min(max(he, 0), FH);
    ws = min(max(ws, 0), FW);
    we = min(max(we, 0), FW);
    // ------------------------------------------------------------------

    float m = 0.0f;
    if (hs < he && ws < we) {
        m = -INFINITY;
        const float* pl = feat + ((size_t)ridx * NCH + c) * PLANE;
        for (int h = hs; h < he; ++h) {
            const float* row = pl + h * FW;
            for (int w = ws; w < we; ++w) {
                m = fmaxf(m, row[w]);
            }
        }
    }
    out[o] = m;
}

extern "C" void kernel_launch(void* const* d_in, const int* in_sizes, int n_in,
                              void* d_out, int out_size, void* d_ws, size_t ws_size,
                              hipStream_t stream) {
    const float* feat = (const float*)d_in[0];
    const int*   rois = (const int*)d_in[1];
    float*       out  = (float*)d_out;

    int blocks = (out_size + 255) / 256;   // 3136 for 64 rois
    roi_pool_kernel<<<blocks, 256, 0, stream>>>(feat, rois, out, out_size);
}